// Round 3
// baseline (457.996 us; speedup 1.0000x reference)
//
#include <hip/hip_runtime.h>
#include <math.h>

// FDTD2DLayer: out = (2*Re(scan(lam2, x@B^T * scaling))) @ C^T + x*D
// Key identities: m1 == 0 (zero input), m3 == conj(m2) since sBu is real,
// so p = 2*Re(m2). `factor` in the reference is dead code.

#define SEQ 8192
#define HDIM 512
#define GS 32
#define G 1024
#define CHUNK 128
#define NCH (SEQ / CHUNK)

__device__ __forceinline__ float softplusf(float z) {
    // stable softplus = max(z,0) + log1p(exp(-|z|))
    return fmaxf(z, 0.0f) + log1pf(expf(-fabsf(z)));
}
__device__ __forceinline__ float clipf(float v, float lo, float hi) {
    return fminf(fmaxf(v, lo), hi);
}

// ---------------------------------------------------------------- params (G threads)
__global__ void params_kernel(const float* __restrict__ c,
                              const float* __restrict__ kp_diag,
                              const float* __restrict__ k_diag,
                              const float* __restrict__ dt_matrix,
                              float* __restrict__ lam_re, float* __restrict__ lam_im,
                              float* __restrict__ scal,
                              float* __restrict__ lamC_re, float* __restrict__ lamC_im) {
    int g = blockIdx.x * blockDim.x + threadIdx.x;
    if (g >= G) return;
    float dt = clipf(expf(dt_matrix[g]), 0.1f, 5.0f);
    float max_c = 0.7f / dt;                       // dx = 1
    float c_pos = clipf(softplusf(c[g]), 0.01f, 0.9f * max_c);

    float kp_base = 0.0f, k_base = 0.0f;
    if (g % (GS + 1) == 0) {                       // diagonal of the GSxGS grid
        int d = g / (GS + 1);
        float kp_d = clipf(softplusf(kp_diag[d]), 1e-4f, 0.2f);
        kp_base = clipf(softplusf(kp_d), 1e-4f, 0.5f);
        float k_d = clipf(softplusf(k_diag[d]), 1e-4f, 0.2f);
        k_base = clipf(softplusf(k_d), 1e-4f, 0.5f);
    }
    float kp_full = clipf(softplusf(kp_base), 1e-4f, 0.5f);
    float k_full  = clipf(softplusf(k_base),  1e-4f, 0.5f);

    float d1 = fmaxf(1.0f + dt * k_full, 0.1f);
    float d2 = fmaxf(1.0f + dt * kp_full, 0.1f);
    float real_part = 0.5f * (1.0f / d2 + 1.0f / d1);
    float c_safe = clipf(c_pos, 0.01f, 1.0f);
    const float xi = 1.5707963267948966f;          // pi/(2*dx)
    float imag_part = clipf(c_safe * dt * xi / sqrtf(fmaxf(d1 * d2, 1e-6f)), -10.0f, 10.0f);

    lam_re[g] = real_part;
    lam_im[g] = imag_part;
    scal[g] = 1.0f / (1.0f + dt * kp_full);

    // lambda^CHUNK (CHUNK = 128 = 2^7) by repeated squaring, for the chunk-carry scan
    float ar = real_part, ai = imag_part;
#pragma unroll
    for (int s = 0; s < 7; ++s) {
        float nr = ar * ar - ai * ai;
        float ni = 2.0f * ar * ai;
        ar = nr; ai = ni;
    }
    lamC_re[g] = ar; lamC_im[g] = ai;
}

// ---------------------------------------------------------------- GEMM: Cout[M,N] = A[M,K] * Bm[N,K]^T
// epilogue: if scal != null -> *= scal[col];  else -> += xres[row,col]*Dv[col]
#define BM 128
#define BN 128
#define KT 16
#define LPAD 4

__global__ __launch_bounds__(256)
void gemm_abt(const float* __restrict__ A, const float* __restrict__ Bm,
              float* __restrict__ Cout, int M, int N, int K,
              const float* __restrict__ scal,
              const float* __restrict__ xres, const float* __restrict__ Dv) {
    __shared__ float As[KT][BM + LPAD];
    __shared__ float Bs[KT][BN + LPAD];
    const int tid = threadIdx.x;
    const int tx = tid & 15, ty = tid >> 4;
    const int m0 = blockIdx.y * BM, n0 = blockIdx.x * BN;
    const int i0 = ty * 8, j0 = tx * 8;

    float acc[8][8] = {};

    for (int kt = 0; kt < K; kt += KT) {
#pragma unroll
        for (int it = 0; it < 2; ++it) {
            int l = tid + it * 256;          // 512 float4 per tile
            int row = l >> 2;                // 0..127
            int kq = (l & 3) * 4;            // 0,4,8,12
            float4 va = *(const float4*)(A + (size_t)(m0 + row) * K + kt + kq);
            As[kq + 0][row] = va.x; As[kq + 1][row] = va.y;
            As[kq + 2][row] = va.z; As[kq + 3][row] = va.w;
            float4 vb = *(const float4*)(Bm + (size_t)(n0 + row) * K + kt + kq);
            Bs[kq + 0][row] = vb.x; Bs[kq + 1][row] = vb.y;
            Bs[kq + 2][row] = vb.z; Bs[kq + 3][row] = vb.w;
        }
        __syncthreads();
#pragma unroll
        for (int k = 0; k < KT; ++k) {
            float a[8], b[8];
#pragma unroll
            for (int u = 0; u < 8; ++u) a[u] = As[k][i0 + u];
#pragma unroll
            for (int v = 0; v < 8; ++v) b[v] = Bs[k][j0 + v];
#pragma unroll
            for (int u = 0; u < 8; ++u)
#pragma unroll
                for (int v = 0; v < 8; ++v)
                    acc[u][v] = fmaf(a[u], b[v], acc[u][v]);
        }
        __syncthreads();
    }

    if (scal) {
        float s[8];
#pragma unroll
        for (int v = 0; v < 8; ++v) s[v] = scal[n0 + j0 + v];
#pragma unroll
        for (int u = 0; u < 8; ++u) {
            float* dst = Cout + (size_t)(m0 + i0 + u) * N + n0 + j0;
            float4 w0 = make_float4(acc[u][0] * s[0], acc[u][1] * s[1],
                                    acc[u][2] * s[2], acc[u][3] * s[3]);
            float4 w1 = make_float4(acc[u][4] * s[4], acc[u][5] * s[5],
                                    acc[u][6] * s[6], acc[u][7] * s[7]);
            *(float4*)dst = w0;
            *(float4*)(dst + 4) = w1;
        }
    } else {
        float dv[8];
#pragma unroll
        for (int v = 0; v < 8; ++v) dv[v] = Dv[n0 + j0 + v];
#pragma unroll
        for (int u = 0; u < 8; ++u) {
            size_t roff = (size_t)(m0 + i0 + u) * N + n0 + j0;
            float4 x0 = *(const float4*)(xres + roff);
            float4 x1 = *(const float4*)(xres + roff + 4);
            float4 w0 = make_float4(fmaf(x0.x, dv[0], acc[u][0]), fmaf(x0.y, dv[1], acc[u][1]),
                                    fmaf(x0.z, dv[2], acc[u][2]), fmaf(x0.w, dv[3], acc[u][3]));
            float4 w1 = make_float4(fmaf(x1.x, dv[4], acc[u][4]), fmaf(x1.y, dv[5], acc[u][5]),
                                    fmaf(x1.z, dv[6], acc[u][6]), fmaf(x1.w, dv[7], acc[u][7]));
            float* dst = Cout + roff;
            *(float4*)dst = w0;
            *(float4*)(dst + 4) = w1;
        }
    }
}

// ---------------------------------------------------------------- scan phase A: per-(column, chunk) local final
__global__ __launch_bounds__(256)
void scan_carry(const float* __restrict__ sBu,
                const float* __restrict__ lam_re, const float* __restrict__ lam_im,
                float2* __restrict__ carry) {
    int g = blockIdx.x * 256 + threadIdx.x;
    int ch = blockIdx.y;
    const float lr = lam_re[g], li = lam_im[g];
    const float* f = sBu + (size_t)ch * CHUNK * G + g;
    float hr = 0.0f, hi = 0.0f;
    for (int tb = 0; tb < CHUNK / 8; ++tb) {
        float fb[8];
#pragma unroll
        for (int u = 0; u < 8; ++u) fb[u] = f[(size_t)(tb * 8 + u) * G];
#pragma unroll
        for (int u = 0; u < 8; ++u) {
            float nr = fmaf(lr, hr, fmaf(-li, hi, fb[u]));
            float ni = fmaf(lr, hi, li * hr);
            hr = nr; hi = ni;
        }
    }
    carry[(size_t)ch * G + g] = make_float2(hr, hi);
}

// ---------------------------------------------------------------- scan phase B: chunk-level scan (G threads, NCH steps)
__global__ void carry_scan(const float2* __restrict__ carry,
                           const float* __restrict__ lamC_re, const float* __restrict__ lamC_im,
                           float2* __restrict__ carry_in) {
    int g = blockIdx.x * blockDim.x + threadIdx.x;
    if (g >= G) return;
    const float lr = lamC_re[g], li = lamC_im[g];
    float hr = 0.0f, hi = 0.0f;
    for (int ch = 0; ch < NCH; ++ch) {
        carry_in[(size_t)ch * G + g] = make_float2(hr, hi);   // h entering chunk ch
        float2 loc = carry[(size_t)ch * G + g];
        float nr = fmaf(lr, hr, -li * hi) + loc.x;
        float ni = fmaf(lr, hi, li * hr) + loc.y;
        hr = nr; hi = ni;
    }
}

// ---------------------------------------------------------------- scan phase C: emit p = 2*Re(h), in place over sBu
__global__ __launch_bounds__(256)
void scan_emit(float* __restrict__ buf,
               const float* __restrict__ lam_re, const float* __restrict__ lam_im,
               const float2* __restrict__ carry_in) {
    int g = blockIdx.x * 256 + threadIdx.x;
    int ch = blockIdx.y;
    const float lr = lam_re[g], li = lam_im[g];
    float* f = buf + (size_t)ch * CHUNK * G + g;
    float2 h0 = carry_in[(size_t)ch * G + g];
    float hr = h0.x, hi = h0.y;
    for (int tb = 0; tb < CHUNK / 8; ++tb) {
        float fb[8];
#pragma unroll
        for (int u = 0; u < 8; ++u) fb[u] = f[(size_t)(tb * 8 + u) * G];
        float pb[8];
#pragma unroll
        for (int u = 0; u < 8; ++u) {
            float nr = fmaf(lr, hr, fmaf(-li, hi, fb[u]));
            float ni = fmaf(lr, hi, li * hr);
            hr = nr; hi = ni;
            pb[u] = 2.0f * hr;
        }
#pragma unroll
        for (int u = 0; u < 8; ++u) f[(size_t)(tb * 8 + u) * G] = pb[u];
    }
}

// ----------------------------------------------------------------
extern "C" void kernel_launch(void* const* d_in, const int* in_sizes, int n_in,
                              void* d_out, int out_size, void* d_ws, size_t ws_size,
                              hipStream_t stream) {
    const float* x   = (const float*)d_in[0];  // (SEQ, H)
    const float* c   = (const float*)d_in[1];  // (G,)
    const float* kp  = (const float*)d_in[2];  // (GS,)
    const float* kd  = (const float*)d_in[3];  // (GS,)
    const float* dtm = (const float*)d_in[4];  // (GS, GS)
    const float* B   = (const float*)d_in[5];  // (G, H)
    const float* C   = (const float*)d_in[6];  // (H, G)
    const float* D   = (const float*)d_in[7];  // (H,)
    float* out = (float*)d_out;                // (SEQ, H)

    float* ws = (float*)d_ws;
    float* sBu     = ws;                          // SEQ*G floats; becomes p in place
    float* lam_re  = ws + (size_t)SEQ * G;
    float* lam_im  = lam_re + G;
    float* scal    = lam_im + G;
    float* lamC_re = scal + G;
    float* lamC_im = lamC_re + G;
    float2* carry    = (float2*)(lamC_im + G);    // NCH*G float2
    float2* carry_in = carry + (size_t)NCH * G;   // NCH*G float2
    // total ws use: (SEQ*G + 5G + 4*NCH*G) * 4B  ~= 34.6 MB

    params_kernel<<<dim3(G / 256), 256, 0, stream>>>(c, kp, kd, dtm, lam_re, lam_im,
                                                     scal, lamC_re, lamC_im);

    // sBu = (x @ B^T) * scaling
    gemm_abt<<<dim3(G / BN, SEQ / BM), 256, 0, stream>>>(x, B, sBu, SEQ, G, HDIM,
                                                         scal, nullptr, nullptr);

    // h[t] = lam2*h[t-1] + sBu[t];  p = 2*Re(h)   (exact 3-phase chunked scan)
    scan_carry<<<dim3(G / 256, NCH), 256, 0, stream>>>(sBu, lam_re, lam_im, carry);
    carry_scan<<<dim3(G / 256), 256, 0, stream>>>(carry, lamC_re, lamC_im, carry_in);
    scan_emit<<<dim3(G / 256, NCH), 256, 0, stream>>>(sBu, lam_re, lam_im, carry_in);

    // out = p @ C^T + x * D
    gemm_abt<<<dim3(HDIM / BN, SEQ / BM), 256, 0, stream>>>(sBu, C, out, SEQ, HDIM, G,
                                                            nullptr, x, D);
}

// Round 7
// 204.278 us; speedup vs baseline: 2.2420x; 2.2420x over previous
//
#include <hip/hip_runtime.h>
#include <math.h>

// FDTD2DLayer: out = (2*Re(scan(lam2, x@B^T * scaling))) @ C^T + x*D
// m1 == 0, m3 == conj(m2) (sBu real, lam3 = conj(lam2)) => p = 2*Re(m2).
// GEMMs: bf16 2-way-split MFMA (hh+hl+lh+ll), fp32 accumulate, rel err ~2^-16.
// Scan stays fp32 (validated R3).

#define SEQ 8192
#define HDIM 512
#define GS 32
#define G 1024
#define CHUNK 128
#define NCH (SEQ / CHUNK)

typedef unsigned short u16;
typedef unsigned int u32;
typedef __attribute__((ext_vector_type(8))) short short8;  // 8 bf16 = 4 VGPR
typedef __attribute__((ext_vector_type(4))) float f32x4;   // MFMA C/D

#define AS1 __attribute__((address_space(1)))
#define AS3 __attribute__((address_space(3)))

__device__ __forceinline__ float softplusf(float z) {
    return fmaxf(z, 0.0f) + log1pf(expf(-fabsf(z)));
}
__device__ __forceinline__ float clipf(float v, float lo, float hi) {
    return fminf(fmaxf(v, lo), hi);
}
// split fp32 -> bf16 hi + bf16 lo; f ≈ hi + lo, |err| <= ~2^-17|f|
__device__ __forceinline__ void split2(float f, u16& h, u16& l) {
    u32 b = __float_as_uint(f);
    u32 hb = (b + 0x8000u) & 0xffff0000u;
    h = (u16)(hb >> 16);
    float r = f - __uint_as_float(hb);          // exact in fp32
    l = (u16)((__float_as_uint(r) + 0x8000u) >> 16);
}

// ---------------------------------------------------------------- params (G threads)
__global__ void params_kernel(const float* __restrict__ c,
                              const float* __restrict__ kp_diag,
                              const float* __restrict__ k_diag,
                              const float* __restrict__ dt_matrix,
                              float* __restrict__ lam_re, float* __restrict__ lam_im,
                              float* __restrict__ scal,
                              float* __restrict__ lamC_re, float* __restrict__ lamC_im) {
    int g = blockIdx.x * blockDim.x + threadIdx.x;
    if (g >= G) return;
    float dt = clipf(expf(dt_matrix[g]), 0.1f, 5.0f);
    float max_c = 0.7f / dt;
    float c_pos = clipf(softplusf(c[g]), 0.01f, 0.9f * max_c);

    float kp_base = 0.0f, k_base = 0.0f;
    if (g % (GS + 1) == 0) {
        int d = g / (GS + 1);
        float kp_d = clipf(softplusf(kp_diag[d]), 1e-4f, 0.2f);
        kp_base = clipf(softplusf(kp_d), 1e-4f, 0.5f);
        float k_d = clipf(softplusf(k_diag[d]), 1e-4f, 0.2f);
        k_base = clipf(softplusf(k_d), 1e-4f, 0.5f);
    }
    float kp_full = clipf(softplusf(kp_base), 1e-4f, 0.5f);
    float k_full  = clipf(softplusf(k_base),  1e-4f, 0.5f);

    float d1 = fmaxf(1.0f + dt * k_full, 0.1f);
    float d2 = fmaxf(1.0f + dt * kp_full, 0.1f);
    float real_part = 0.5f * (1.0f / d2 + 1.0f / d1);
    float c_safe = clipf(c_pos, 0.01f, 1.0f);
    const float xi = 1.5707963267948966f;
    float imag_part = clipf(c_safe * dt * xi / sqrtf(fmaxf(d1 * d2, 1e-6f)), -10.0f, 10.0f);

    lam_re[g] = real_part;
    lam_im[g] = imag_part;
    scal[g] = 1.0f / (1.0f + dt * kp_full);

    float ar = real_part, ai = imag_part;       // lambda^CHUNK by squaring
#pragma unroll
    for (int s = 0; s < 7; ++s) {
        float nr = ar * ar - ai * ai;
        float ni = 2.0f * ar * ai;
        ar = nr; ai = ni;
    }
    lamC_re[g] = ar; lamC_im[g] = ai;
}

// ---------------------------------------------------------------- fp32 -> (bf16h, bf16l)
__global__ __launch_bounds__(256)
void split_bf16(const float* __restrict__ in, u16* __restrict__ hi,
                u16* __restrict__ lo, int n4) {
    int stride = gridDim.x * 256;
    for (int i = blockIdx.x * 256 + threadIdx.x; i < n4; i += stride) {
        float4 v = ((const float4*)in)[i];
        ushort4 h, l;
        split2(v.x, h.x, l.x); split2(v.y, h.y, l.y);
        split2(v.z, h.z, l.z); split2(v.w, h.w, l.w);
        ((ushort4*)hi)[i] = h;
        ((ushort4*)lo)[i] = l;
    }
}

// ---------------------------------------------------------------- split-bf16 MFMA GEMM
// Cout[M,N] = (Ah+Al)[M,K] * (Bh+Bl)[N,K]^T   (bf16 row-major, K-contig)
// 2x2 waves of WMxWN; BK=32; 2-phase global_load_lds pipeline (§5.5 T3-min).
// LDS swizzle: physical 16B slot (row,hp) holds logical k-chunk hp ^ ((row>>1)&3).
// Involution applied on the GLOBAL source at stage + on the ds_read index;
// LDS dest stays linear (rule #21). Leaves only free 2-way bank aliasing.
template<int BM, int BN, int WM, int WN, bool SCALE_EPI>
__global__ __launch_bounds__(256, 2)
void gemm_split(const u16* __restrict__ Ah, const u16* __restrict__ Al,
                const u16* __restrict__ Bh, const u16* __restrict__ Bl,
                float* __restrict__ Cout, int M, int N, int K,
                const float* __restrict__ scal,
                const float* __restrict__ xres, const float* __restrict__ Dv) {
    constexpr int MI = WM / 16, NI = WN / 16;
    constexpr int ACH = BM / 16, BCH = BN / 16;            // 1KB chunks (16 rows x 32 u16)
    constexpr int oAh = 0, oAl = BM * 32;
    constexpr int oBh = 2 * BM * 32, oBl = 2 * BM * 32 + BN * 32;
    constexpr int BUFS = 2 * BM * 32 + 2 * BN * 32;        // u16 per buffer
    __shared__ __align__(16) u16 sm[2][BUFS];

    const int tid = threadIdx.x;
    const int lane = tid & 63, wid = tid >> 6;
    const int wrow = wid >> 1, wcol = wid & 1;
    const int lr = lane & 15, lg = lane >> 4;
    const int m0 = blockIdx.y * BM, n0 = blockIdx.x * BN;

    const u16* gbs[4]   = {Ah, Al, Bh, Bl};
    const int  nchs[4]  = {ACH, ACH, BCH, BCH};
    const int  row0s[4] = {m0, m0, n0, n0};
    const int  ofss[4]  = {oAh, oAl, oBh, oBl};

    const int srow = lane >> 2;        // row-in-chunk 0..15
    const int shp  = lane & 3;         // physical 16B slot in row

    auto stage = [&](int buf, int kt) {
#pragma unroll
        for (int a = 0; a < 4; ++a) {
            for (int c = wid; c < nchs[a]; c += 4) {
                int r = c * 16 + srow;
                int h = shp ^ ((r >> 1) & 3);              // inverse swizzle on source
                const u16* gp = gbs[a] + (size_t)(row0s[a] + r) * K + kt + h * 8;
                u16* lp = &sm[buf][ofss[a] + c * 512];     // wave-uniform, linear dest
                __builtin_amdgcn_global_load_lds((const AS1 u32*)gp, (AS3 u32*)lp, 16, 0, 0);
            }
        }
    };

    f32x4 acc[MI][NI];
#pragma unroll
    for (int i = 0; i < MI; ++i)
#pragma unroll
        for (int j = 0; j < NI; ++j) acc[i][j] = (f32x4){0.f, 0.f, 0.f, 0.f};

    stage(0, 0);
    __syncthreads();

    const int NT = K / 32;
    for (int t = 0; t < NT; ++t) {
        const int buf = t & 1;
        if (t + 1 < NT) stage(buf ^ 1, (t + 1) * 32);      // prefetch next K-tile

        short8 fah[MI], fal[MI], fbh[NI], fbl[NI];
#pragma unroll
        for (int mi = 0; mi < MI; ++mi) {
            int r = wrow * WM + mi * 16 + lr;
            int idx = r * 32 + ((lg ^ ((r >> 1) & 3)) * 8);   // swizzled read
            fah[mi] = *(const short8*)&sm[buf][oAh + idx];
            fal[mi] = *(const short8*)&sm[buf][oAl + idx];
        }
#pragma unroll
        for (int ni = 0; ni < NI; ++ni) {
            int r = wcol * WN + ni * 16 + lr;
            int idx = r * 32 + ((lg ^ ((r >> 1) & 3)) * 8);
            fbh[ni] = *(const short8*)&sm[buf][oBh + idx];
            fbl[ni] = *(const short8*)&sm[buf][oBl + idx];
        }
#pragma unroll
        for (int mi = 0; mi < MI; ++mi)
#pragma unroll
            for (int ni = 0; ni < NI; ++ni) {
                acc[mi][ni] = __builtin_amdgcn_mfma_f32_16x16x32_bf16(fah[mi], fbh[ni], acc[mi][ni], 0, 0, 0);
                acc[mi][ni] = __builtin_amdgcn_mfma_f32_16x16x32_bf16(fah[mi], fbl[ni], acc[mi][ni], 0, 0, 0);
                acc[mi][ni] = __builtin_amdgcn_mfma_f32_16x16x32_bf16(fal[mi], fbh[ni], acc[mi][ni], 0, 0, 0);
                acc[mi][ni] = __builtin_amdgcn_mfma_f32_16x16x32_bf16(fal[mi], fbl[ni], acc[mi][ni], 0, 0, 0);
            }
        __syncthreads();
    }

    // C/D layout (HW-verified, §3): col = lane&15, row = (lane>>4)*4 + v
#pragma unroll
    for (int mi = 0; mi < MI; ++mi)
#pragma unroll
        for (int ni = 0; ni < NI; ++ni) {
            int col = n0 + wcol * WN + ni * 16 + lr;
            int rbase = m0 + wrow * WM + mi * 16 + lg * 4;
            if constexpr (SCALE_EPI) {
                float s = scal[col];
#pragma unroll
                for (int v = 0; v < 4; ++v)
                    Cout[(size_t)(rbase + v) * N + col] = acc[mi][ni][v] * s;
            } else {
                float dv = Dv[col];
#pragma unroll
                for (int v = 0; v < 4; ++v) {
                    size_t o = (size_t)(rbase + v) * N + col;
                    Cout[o] = fmaf(xres[o], dv, acc[mi][ni][v]);
                }
            }
        }
}

// ---------------------------------------------------------------- scan phase A
__global__ __launch_bounds__(256)
void scan_carry(const float* __restrict__ sBu,
                const float* __restrict__ lam_re, const float* __restrict__ lam_im,
                float2* __restrict__ carry) {
    int g = blockIdx.x * 256 + threadIdx.x;
    int ch = blockIdx.y;
    const float lr = lam_re[g], li = lam_im[g];
    const float* f = sBu + (size_t)ch * CHUNK * G + g;
    float hr = 0.0f, hi = 0.0f;
    for (int tb = 0; tb < CHUNK / 8; ++tb) {
        float fb[8];
#pragma unroll
        for (int u = 0; u < 8; ++u) fb[u] = f[(size_t)(tb * 8 + u) * G];
#pragma unroll
        for (int u = 0; u < 8; ++u) {
            float nr = fmaf(lr, hr, fmaf(-li, hi, fb[u]));
            float ni = fmaf(lr, hi, li * hr);
            hr = nr; hi = ni;
        }
    }
    carry[(size_t)ch * G + g] = make_float2(hr, hi);
}

// ---------------------------------------------------------------- scan phase B
__global__ void carry_scan(const float2* __restrict__ carry,
                           const float* __restrict__ lamC_re, const float* __restrict__ lamC_im,
                           float2* __restrict__ carry_in) {
    int g = blockIdx.x * blockDim.x + threadIdx.x;
    if (g >= G) return;
    const float lr = lamC_re[g], li = lamC_im[g];
    float hr = 0.0f, hi = 0.0f;
    for (int ch = 0; ch < NCH; ++ch) {
        carry_in[(size_t)ch * G + g] = make_float2(hr, hi);
        float2 loc = carry[(size_t)ch * G + g];
        float nr = fmaf(lr, hr, -li * hi) + loc.x;
        float ni = fmaf(lr, hi, li * hr) + loc.y;
        hr = nr; hi = ni;
    }
}

// ---------------------------------------------------------------- scan phase C: p = 2*Re(h) -> bf16 h/l
__global__ __launch_bounds__(256)
void scan_emit(const float* __restrict__ sBu, u16* __restrict__ ph, u16* __restrict__ pl,
               const float* __restrict__ lam_re, const float* __restrict__ lam_im,
               const float2* __restrict__ carry_in) {
    int g = blockIdx.x * 256 + threadIdx.x;
    int ch = blockIdx.y;
    const float lr = lam_re[g], li = lam_im[g];
    const float* f = sBu + (size_t)ch * CHUNK * G + g;
    u16* oh = ph + (size_t)ch * CHUNK * G + g;
    u16* ol = pl + (size_t)ch * CHUNK * G + g;
    float2 h0 = carry_in[(size_t)ch * G + g];
    float hr = h0.x, hi = h0.y;
    for (int tb = 0; tb < CHUNK / 8; ++tb) {
        float fb[8];
#pragma unroll
        for (int u = 0; u < 8; ++u) fb[u] = f[(size_t)(tb * 8 + u) * G];
#pragma unroll
        for (int u = 0; u < 8; ++u) {
            float nr = fmaf(lr, hr, fmaf(-li, hi, fb[u]));
            float ni = fmaf(lr, hi, li * hr);
            hr = nr; hi = ni;
            float p = 2.0f * hr;
            u16 hh, ll; split2(p, hh, ll);
            oh[(size_t)(tb * 8 + u) * G] = hh;
            ol[(size_t)(tb * 8 + u) * G] = ll;
        }
    }
}

// ----------------------------------------------------------------
extern "C" void kernel_launch(void* const* d_in, const int* in_sizes, int n_in,
                              void* d_out, int out_size, void* d_ws, size_t ws_size,
                              hipStream_t stream) {
    const float* x   = (const float*)d_in[0];  // (SEQ, H)
    const float* c   = (const float*)d_in[1];
    const float* kp  = (const float*)d_in[2];
    const float* kd  = (const float*)d_in[3];
    const float* dtm = (const float*)d_in[4];
    const float* B   = (const float*)d_in[5];  // (G, H)  -> GEMM1 B-operand [N=G][K=H]
    const float* Cm  = (const float*)d_in[6];  // (H, G)  -> GEMM2 B-operand [N=H][K=G]
    const float* D   = (const float*)d_in[7];
    float* out = (float*)d_out;                // (SEQ, H)

    char* w = (char*)d_ws;
    float* sBu = (float*)w;              w += (size_t)SEQ * G * 4;      // fp32 scan input
    u16* ph = (u16*)w;                   w += (size_t)SEQ * G * 2;
    u16* pl = (u16*)w;                   w += (size_t)SEQ * G * 2;
    u16* xh = (u16*)w;                   w += (size_t)SEQ * HDIM * 2;
    u16* xl = (u16*)w;                   w += (size_t)SEQ * HDIM * 2;
    u16* Bh_ = (u16*)w;                  w += (size_t)G * HDIM * 2;
    u16* Bl_ = (u16*)w;                  w += (size_t)G * HDIM * 2;
    u16* Ch_ = (u16*)w;                  w += (size_t)HDIM * G * 2;
    u16* Cl_ = (u16*)w;                  w += (size_t)HDIM * G * 2;
    float* lam_re  = (float*)w;          w += G * 4;
    float* lam_im  = (float*)w;          w += G * 4;
    float* scal    = (float*)w;          w += G * 4;
    float* lamC_re = (float*)w;          w += G * 4;
    float* lamC_im = (float*)w;          w += G * 4;
    float2* carry    = (float2*)w;       w += (size_t)NCH * G * 8;
    float2* carry_in = (float2*)w;       // total ~93 MB

    params_kernel<<<dim3(G / 256), 256, 0, stream>>>(c, kp, kd, dtm, lam_re, lam_im,
                                                     scal, lamC_re, lamC_im);
    split_bf16<<<dim3(2048), 256, 0, stream>>>(x,  xh,  xl,  SEQ * HDIM / 4);
    split_bf16<<<dim3(512),  256, 0, stream>>>(B,  Bh_, Bl_, G * HDIM / 4);
    split_bf16<<<dim3(512),  256, 0, stream>>>(Cm, Ch_, Cl_, HDIM * G / 4);

    // sBu = (x @ B^T) * scaling   — M=8192, N=1024, K=512
    gemm_split<128, 128, 64, 64, true>
        <<<dim3(G / 128, SEQ / 128), 256, 0, stream>>>(xh, xl, Bh_, Bl_, sBu,
                                                       SEQ, G, HDIM, scal, nullptr, nullptr);

    scan_carry<<<dim3(G / 256, NCH), 256, 0, stream>>>(sBu, lam_re, lam_im, carry);
    carry_scan<<<dim3(G / 256), 256, 0, stream>>>(carry, lamC_re, lamC_im, carry_in);
    scan_emit<<<dim3(G / 256, NCH), 256, 0, stream>>>(sBu, ph, pl, lam_re, lam_im, carry_in);

    // out = p @ C^T + x*D   — M=8192, N=512, K=1024; BN=64 keeps grid at 512 blocks (2/CU)
    gemm_split<128, 64, 64, 32, false>
        <<<dim3(HDIM / 64, SEQ / 128), 256, 0, stream>>>(ph, pl, Ch_, Cl_, out,
                                                         SEQ, HDIM, G, nullptr, x, D);
}

// Round 8
// 184.401 us; speedup vs baseline: 2.4837x; 1.1078x over previous
//
#include <hip/hip_runtime.h>
#include <math.h>

// FDTD2DLayer: out = (2*Re(scan(lam2, x@B^T * scaling))) @ C^T + x*D
// m1 == 0, m3 == conj(m2) (sBu real, lam3 = conj(lam2)) => p = 2*Re(m2).
// GEMMs: bf16 2-way-split MFMA, 3-product (hh+hl+lh; ll term <= 2^-18 rel,
// same order as split representation error). fp32 accumulate.
// R7 measured: swizzled staging -> 0 bank conflicts; adding T1 XCD swizzle
// (A-panels were re-fetched per XCD: 140 MB vs 54 MB ideal on GEMM2).

#define SEQ 8192
#define HDIM 512
#define GS 32
#define G 1024
#define CHUNK 128
#define NCH (SEQ / CHUNK)

typedef unsigned short u16;
typedef unsigned int u32;
typedef __attribute__((ext_vector_type(8))) short short8;  // 8 bf16 = 4 VGPR
typedef __attribute__((ext_vector_type(4))) float f32x4;   // MFMA C/D

#define AS1 __attribute__((address_space(1)))
#define AS3 __attribute__((address_space(3)))

__device__ __forceinline__ float softplusf(float z) {
    return fmaxf(z, 0.0f) + log1pf(expf(-fabsf(z)));
}
__device__ __forceinline__ float clipf(float v, float lo, float hi) {
    return fminf(fmaxf(v, lo), hi);
}
// split fp32 -> bf16 hi + bf16 lo; f ≈ hi + lo, |err| <= ~2^-17|f|
__device__ __forceinline__ void split2(float f, u16& h, u16& l) {
    u32 b = __float_as_uint(f);
    u32 hb = (b + 0x8000u) & 0xffff0000u;
    h = (u16)(hb >> 16);
    float r = f - __uint_as_float(hb);          // exact in fp32
    l = (u16)((__float_as_uint(r) + 0x8000u) >> 16);
}

// ---------------------------------------------------------------- params (G threads)
__global__ void params_kernel(const float* __restrict__ c,
                              const float* __restrict__ kp_diag,
                              const float* __restrict__ k_diag,
                              const float* __restrict__ dt_matrix,
                              float* __restrict__ lam_re, float* __restrict__ lam_im,
                              float* __restrict__ scal,
                              float* __restrict__ lamC_re, float* __restrict__ lamC_im) {
    int g = blockIdx.x * blockDim.x + threadIdx.x;
    if (g >= G) return;
    float dt = clipf(expf(dt_matrix[g]), 0.1f, 5.0f);
    float max_c = 0.7f / dt;
    float c_pos = clipf(softplusf(c[g]), 0.01f, 0.9f * max_c);

    float kp_base = 0.0f, k_base = 0.0f;
    if (g % (GS + 1) == 0) {
        int d = g / (GS + 1);
        float kp_d = clipf(softplusf(kp_diag[d]), 1e-4f, 0.2f);
        kp_base = clipf(softplusf(kp_d), 1e-4f, 0.5f);
        float k_d = clipf(softplusf(k_diag[d]), 1e-4f, 0.2f);
        k_base = clipf(softplusf(k_d), 1e-4f, 0.5f);
    }
    float kp_full = clipf(softplusf(kp_base), 1e-4f, 0.5f);
    float k_full  = clipf(softplusf(k_base),  1e-4f, 0.5f);

    float d1 = fmaxf(1.0f + dt * k_full, 0.1f);
    float d2 = fmaxf(1.0f + dt * kp_full, 0.1f);
    float real_part = 0.5f * (1.0f / d2 + 1.0f / d1);
    float c_safe = clipf(c_pos, 0.01f, 1.0f);
    const float xi = 1.5707963267948966f;
    float imag_part = clipf(c_safe * dt * xi / sqrtf(fmaxf(d1 * d2, 1e-6f)), -10.0f, 10.0f);

    lam_re[g] = real_part;
    lam_im[g] = imag_part;
    scal[g] = 1.0f / (1.0f + dt * kp_full);

    float ar = real_part, ai = imag_part;       // lambda^CHUNK by squaring
#pragma unroll
    for (int s = 0; s < 7; ++s) {
        float nr = ar * ar - ai * ai;
        float ni = 2.0f * ar * ai;
        ar = nr; ai = ni;
    }
    lamC_re[g] = ar; lamC_im[g] = ai;
}

// ---------------------------------------------------------------- fp32 -> (bf16h, bf16l)
__global__ __launch_bounds__(256)
void split_bf16(const float* __restrict__ in, u16* __restrict__ hi,
                u16* __restrict__ lo, int n4) {
    int stride = gridDim.x * 256;
    for (int i = blockIdx.x * 256 + threadIdx.x; i < n4; i += stride) {
        float4 v = ((const float4*)in)[i];
        ushort4 h, l;
        split2(v.x, h.x, l.x); split2(v.y, h.y, l.y);
        split2(v.z, h.z, l.z); split2(v.w, h.w, l.w);
        ((ushort4*)hi)[i] = h;
        ((ushort4*)lo)[i] = l;
    }
}

// ---------------------------------------------------------------- split-bf16 MFMA GEMM
// Cout[M,N] = (Ah+Al)[M,K] * (Bh+Bl)[N,K]^T   (bf16 row-major, K-contig)
// 2x2 waves of WMxWN; BK=32; 2-phase global_load_lds pipeline (§5.5 T3-min).
// LDS swizzle: physical 16B slot (row,hp) holds logical k-chunk hp ^ ((row>>1)&3).
// Involution on GLOBAL source at stage + on ds_read index; LDS dest linear
// (rule #21). R7: SQ_LDS_BANK_CONFLICT == 0 confirmed.
// T1 XCD swizzle: flat%8 == XCD (round-robin dispatch) -> give each XCD a
// contiguous m-panel range so A row-panels become per-XCD-L2 hits.
template<int BM, int BN, int WM, int WN, bool SCALE_EPI>
__global__ __launch_bounds__(256, 2)
void gemm_split(const u16* __restrict__ Ah, const u16* __restrict__ Al,
                const u16* __restrict__ Bh, const u16* __restrict__ Bl,
                float* __restrict__ Cout, int M, int N, int K,
                const float* __restrict__ scal,
                const float* __restrict__ xres, const float* __restrict__ Dv) {
    constexpr int MI = WM / 16, NI = WN / 16;
    constexpr int ACH = BM / 16, BCH = BN / 16;            // 1KB chunks (16 rows x 32 u16)
    constexpr int oAh = 0, oAl = BM * 32;
    constexpr int oBh = 2 * BM * 32, oBl = 2 * BM * 32 + BN * 32;
    constexpr int BUFS = 2 * BM * 32 + 2 * BN * 32;        // u16 per buffer
    __shared__ __align__(16) u16 sm[2][BUFS];

    const int tid = threadIdx.x;
    const int lane = tid & 63, wid = tid >> 6;
    const int wrow = wid >> 1, wcol = wid & 1;
    const int lr = lane & 15, lg = lane >> 4;

    // T1: bijective XCD swizzle (nwg % 8 == 0 for both grids: 512)
    const int flat = blockIdx.y * gridDim.x + blockIdx.x;
    const int cpx = (gridDim.x * gridDim.y) >> 3;
    const int swz = (flat & 7) * cpx + (flat >> 3);
    const int m0 = (swz / gridDim.x) * BM, n0 = (swz % gridDim.x) * BN;

    const u16* gbs[4]   = {Ah, Al, Bh, Bl};
    const int  nchs[4]  = {ACH, ACH, BCH, BCH};
    const int  row0s[4] = {m0, m0, n0, n0};
    const int  ofss[4]  = {oAh, oAl, oBh, oBl};

    const int srow = lane >> 2;        // row-in-chunk 0..15
    const int shp  = lane & 3;         // physical 16B slot in row

    auto stage = [&](int buf, int kt) {
#pragma unroll
        for (int a = 0; a < 4; ++a) {
            for (int c = wid; c < nchs[a]; c += 4) {
                int r = c * 16 + srow;
                int h = shp ^ ((r >> 1) & 3);              // inverse swizzle on source
                const u16* gp = gbs[a] + (size_t)(row0s[a] + r) * K + kt + h * 8;
                u16* lp = &sm[buf][ofss[a] + c * 512];     // wave-uniform, linear dest
                __builtin_amdgcn_global_load_lds((const AS1 u32*)gp, (AS3 u32*)lp, 16, 0, 0);
            }
        }
    };

    f32x4 acc[MI][NI];
#pragma unroll
    for (int i = 0; i < MI; ++i)
#pragma unroll
        for (int j = 0; j < NI; ++j) acc[i][j] = (f32x4){0.f, 0.f, 0.f, 0.f};

    stage(0, 0);
    __syncthreads();

    const int NT = K / 32;
    for (int t = 0; t < NT; ++t) {
        const int buf = t & 1;
        if (t + 1 < NT) stage(buf ^ 1, (t + 1) * 32);      // prefetch next K-tile

        short8 fah[MI], fal[MI], fbh[NI], fbl[NI];
#pragma unroll
        for (int mi = 0; mi < MI; ++mi) {
            int r = wrow * WM + mi * 16 + lr;
            int idx = r * 32 + ((lg ^ ((r >> 1) & 3)) * 8);   // swizzled read
            fah[mi] = *(const short8*)&sm[buf][oAh + idx];
            fal[mi] = *(const short8*)&sm[buf][oAl + idx];
        }
#pragma unroll
        for (int ni = 0; ni < NI; ++ni) {
            int r = wcol * WN + ni * 16 + lr;
            int idx = r * 32 + ((lg ^ ((r >> 1) & 3)) * 8);
            fbh[ni] = *(const short8*)&sm[buf][oBh + idx];
            fbl[ni] = *(const short8*)&sm[buf][oBl + idx];
        }
        // 3-product split: hh + hl + lh (ll dropped, <= 2^-18 rel)
#pragma unroll
        for (int mi = 0; mi < MI; ++mi)
#pragma unroll
            for (int ni = 0; ni < NI; ++ni) {
                acc[mi][ni] = __builtin_amdgcn_mfma_f32_16x16x32_bf16(fah[mi], fbh[ni], acc[mi][ni], 0, 0, 0);
                acc[mi][ni] = __builtin_amdgcn_mfma_f32_16x16x32_bf16(fah[mi], fbl[ni], acc[mi][ni], 0, 0, 0);
                acc[mi][ni] = __builtin_amdgcn_mfma_f32_16x16x32_bf16(fal[mi], fbh[ni], acc[mi][ni], 0, 0, 0);
            }
        __syncthreads();
    }

    // C/D layout (HW-verified, §3): col = lane&15, row = (lane>>4)*4 + v
#pragma unroll
    for (int mi = 0; mi < MI; ++mi)
#pragma unroll
        for (int ni = 0; ni < NI; ++ni) {
            int col = n0 + wcol * WN + ni * 16 + lr;
            int rbase = m0 + wrow * WM + mi * 16 + lg * 4;
            if constexpr (SCALE_EPI) {
                float s = scal[col];
#pragma unroll
                for (int v = 0; v < 4; ++v)
                    Cout[(size_t)(rbase + v) * N + col] = acc[mi][ni][v] * s;
            } else {
                float dv = Dv[col];
#pragma unroll
                for (int v = 0; v < 4; ++v) {
                    size_t o = (size_t)(rbase + v) * N + col;
                    Cout[o] = fmaf(xres[o], dv, acc[mi][ni][v]);
                }
            }
        }
}

// ---------------------------------------------------------------- scan phase A
__global__ __launch_bounds__(256)
void scan_carry(const float* __restrict__ sBu,
                const float* __restrict__ lam_re, const float* __restrict__ lam_im,
                float2* __restrict__ carry) {
    int g = blockIdx.x * 256 + threadIdx.x;
    int ch = blockIdx.y;
    const float lr = lam_re[g], li = lam_im[g];
    const float* f = sBu + (size_t)ch * CHUNK * G + g;
    float hr = 0.0f, hi = 0.0f;
    for (int tb = 0; tb < CHUNK / 8; ++tb) {
        float fb[8];
#pragma unroll
        for (int u = 0; u < 8; ++u) fb[u] = f[(size_t)(tb * 8 + u) * G];
#pragma unroll
        for (int u = 0; u < 8; ++u) {
            float nr = fmaf(lr, hr, fmaf(-li, hi, fb[u]));
            float ni = fmaf(lr, hi, li * hr);
            hr = nr; hi = ni;
        }
    }
    carry[(size_t)ch * G + g] = make_float2(hr, hi);
}

// ---------------------------------------------------------------- scan phase B
// Batched prefetch: 8 independent loads then 8 recurrence steps (latency/8).
__global__ void carry_scan(const float2* __restrict__ carry,
                           const float* __restrict__ lamC_re, const float* __restrict__ lamC_im,
                           float2* __restrict__ carry_in) {
    int g = blockIdx.x * blockDim.x + threadIdx.x;
    if (g >= G) return;
    const float lr = lamC_re[g], li = lamC_im[g];
    float hr = 0.0f, hi = 0.0f;
    for (int cb = 0; cb < NCH; cb += 8) {
        float2 loc[8];
#pragma unroll
        for (int u = 0; u < 8; ++u) loc[u] = carry[(size_t)(cb + u) * G + g];
#pragma unroll
        for (int u = 0; u < 8; ++u) {
            carry_in[(size_t)(cb + u) * G + g] = make_float2(hr, hi);
            float nr = fmaf(lr, hr, -li * hi) + loc[u].x;
            float ni = fmaf(lr, hi, li * hr) + loc[u].y;
            hr = nr; hi = ni;
        }
    }
}

// ---------------------------------------------------------------- scan phase C: p = 2*Re(h) -> bf16 h/l
__global__ __launch_bounds__(256)
void scan_emit(const float* __restrict__ sBu, u16* __restrict__ ph, u16* __restrict__ pl,
               const float* __restrict__ lam_re, const float* __restrict__ lam_im,
               const float2* __restrict__ carry_in) {
    int g = blockIdx.x * 256 + threadIdx.x;
    int ch = blockIdx.y;
    const float lr = lam_re[g], li = lam_im[g];
    const float* f = sBu + (size_t)ch * CHUNK * G + g;
    u16* oh = ph + (size_t)ch * CHUNK * G + g;
    u16* ol = pl + (size_t)ch * CHUNK * G + g;
    float2 h0 = carry_in[(size_t)ch * G + g];
    float hr = h0.x, hi = h0.y;
    for (int tb = 0; tb < CHUNK / 8; ++tb) {
        float fb[8];
#pragma unroll
        for (int u = 0; u < 8; ++u) fb[u] = f[(size_t)(tb * 8 + u) * G];
#pragma unroll
        for (int u = 0; u < 8; ++u) {
            float nr = fmaf(lr, hr, fmaf(-li, hi, fb[u]));
            float ni = fmaf(lr, hi, li * hr);
            hr = nr; hi = ni;
            float p = 2.0f * hr;
            u16 hh, ll; split2(p, hh, ll);
            oh[(size_t)(tb * 8 + u) * G] = hh;
            ol[(size_t)(tb * 8 + u) * G] = ll;
        }
    }
}

// ----------------------------------------------------------------
extern "C" void kernel_launch(void* const* d_in, const int* in_sizes, int n_in,
                              void* d_out, int out_size, void* d_ws, size_t ws_size,
                              hipStream_t stream) {
    const float* x   = (const float*)d_in[0];  // (SEQ, H)
    const float* c   = (const float*)d_in[1];
    const float* kp  = (const float*)d_in[2];
    const float* kd  = (const float*)d_in[3];
    const float* dtm = (const float*)d_in[4];
    const float* B   = (const float*)d_in[5];  // (G, H)  -> GEMM1 B-operand [N=G][K=H]
    const float* Cm  = (const float*)d_in[6];  // (H, G)  -> GEMM2 B-operand [N=H][K=G]
    const float* D   = (const float*)d_in[7];
    float* out = (float*)d_out;                // (SEQ, H)

    char* w = (char*)d_ws;
    float* sBu = (float*)w;              w += (size_t)SEQ * G * 4;      // fp32 scan input
    u16* ph = (u16*)w;                   w += (size_t)SEQ * G * 2;
    u16* pl = (u16*)w;                   w += (size_t)SEQ * G * 2;
    u16* xh = (u16*)w;                   w += (size_t)SEQ * HDIM * 2;
    u16* xl = (u16*)w;                   w += (size_t)SEQ * HDIM * 2;
    u16* Bh_ = (u16*)w;                  w += (size_t)G * HDIM * 2;
    u16* Bl_ = (u16*)w;                  w += (size_t)G * HDIM * 2;
    u16* Ch_ = (u16*)w;                  w += (size_t)HDIM * G * 2;
    u16* Cl_ = (u16*)w;                  w += (size_t)HDIM * G * 2;
    float* lam_re  = (float*)w;          w += G * 4;
    float* lam_im  = (float*)w;          w += G * 4;
    float* scal    = (float*)w;          w += G * 4;
    float* lamC_re = (float*)w;          w += G * 4;
    float* lamC_im = (float*)w;          w += G * 4;
    float2* carry    = (float2*)w;       w += (size_t)NCH * G * 8;
    float2* carry_in = (float2*)w;       // total ~93 MB

    params_kernel<<<dim3(G / 256), 256, 0, stream>>>(c, kp, kd, dtm, lam_re, lam_im,
                                                     scal, lamC_re, lamC_im);
    split_bf16<<<dim3(2048), 256, 0, stream>>>(x,  xh,  xl,  SEQ * HDIM / 4);
    split_bf16<<<dim3(512),  256, 0, stream>>>(B,  Bh_, Bl_, G * HDIM / 4);
    split_bf16<<<dim3(512),  256, 0, stream>>>(Cm, Ch_, Cl_, HDIM * G / 4);

    // sBu = (x @ B^T) * scaling   — M=8192, N=1024, K=512
    gemm_split<128, 128, 64, 64, true>
        <<<dim3(G / 128, SEQ / 128), 256, 0, stream>>>(xh, xl, Bh_, Bl_, sBu,
                                                       SEQ, G, HDIM, scal, nullptr, nullptr);

    scan_carry<<<dim3(G / 256, NCH), 256, 0, stream>>>(sBu, lam_re, lam_im, carry);
    carry_scan<<<dim3(G / 256), 256, 0, stream>>>(carry, lamC_re, lamC_im, carry_in);
    scan_emit<<<dim3(G / 256, NCH), 256, 0, stream>>>(sBu, ph, pl, lam_re, lam_im, carry_in);

    // out = p @ C^T + x*D   — M=8192, N=512, K=1024
    gemm_split<128, 64, 64, 32, false>
        <<<dim3(HDIM / 64, SEQ / 128), 256, 0, stream>>>(ph, pl, Ch_, Cl_, out,
                                                         SEQ, HDIM, G, nullptr, x, D);
}